// Round 23
// baseline (328.959 us; speedup 1.0000x reference)
//
#include <hip/hip_runtime.h>

typedef __bf16 bf16;
typedef __bf16 bf16x8 __attribute__((ext_vector_type(8)));
typedef __bf16 bf16x4 __attribute__((ext_vector_type(4)));
typedef float f32x4 __attribute__((ext_vector_type(4)));
typedef unsigned int u32;
typedef unsigned short u16;

#define MFMA_BF16 __builtin_amdgcn_mfma_f32_16x16x32_bf16

#define GLOAD_LDS(g, l)                                        \
  __builtin_amdgcn_global_load_lds(                            \
      (__attribute__((address_space(1))) void*)(g),            \
      (__attribute__((address_space(3))) void*)(l), 16, 0, 0)

// ---------------------------------------------------------------- utilities
__global__ void cvt_f32_bf16(const float* __restrict__ in, bf16* __restrict__ out, int n) {
  int i = (blockIdx.x * blockDim.x + threadIdx.x) * 4;
  if (i >= n) return;
  float4 v = *(const float4*)(in + i);
  bf16x4 o;
  o[0] = (bf16)v.x; o[1] = (bf16)v.y; o[2] = (bf16)v.z; o[3] = (bf16)v.w;
  *(bf16x4*)(out + i) = o;
}

// W [K][N] fp32 -> Wt [N][K] bf16
__global__ void transpose_w(const float* __restrict__ w, bf16* __restrict__ wt, int K, int N) {
  __shared__ float tile[32][33];
  int n0 = blockIdx.x * 32, k0 = blockIdx.y * 32;
  int t = threadIdx.x;
  int c = t & 31, r = t >> 5;
#pragma unroll
  for (int i = 0; i < 4; i++)
    tile[r + i * 8][c] = w[(size_t)(k0 + r + i * 8) * N + n0 + c];
  __syncthreads();
#pragma unroll
  for (int i = 0; i < 4; i++)
    wt[(size_t)(n0 + r + i * 8) * K + k0 + c] = (bf16)tile[c][r + i * 8];
}

__device__ inline float gelu_exact(float x) {
  return 0.5f * x * (1.0f + erff(x * 0.70710678118654752f));
}

// ---------------------------------------------------------------- GEMM
// R22 structure, BK=128 for ALL four GEMMs now: R22 measured BK=128@
// 2 blocks/CU (ff2 ~880+ TF) beating BK=64@3 blocks (ff1 799 TF) — each
// co-residency slot covers 64 MFMA per barrier-drain instead of 32.
// 128x128 tile, 4 waves 2Mx2N, wave tile 64x64, acc[4][4], single-buffered
// LDS (64KB), 2 barriers per K-step of BK. Rows are CH=BK/8 16B chunks;
// read chunk (kk*4+g) ^ (l15&(CH-1)); staging source chunk
// (tid&(CH-1)) ^ ((tid/CH)&(CH-1)) (involution inverse; LDS dest linear).
// Supertile XCD L2 order. MODE 0 pre-scales Q columns by 0.125.
template <int MODE, int BK>
__global__ __launch_bounds__(256, (BK == 128) ? 2 : 3) void gemm_bt(
    const bf16* __restrict__ A, const bf16* __restrict__ Bt,
    bf16* __restrict__ outb, float* __restrict__ outf,
    const float* __restrict__ residf, const bf16* __restrict__ residb,
    int K, int N) {
  constexpr int CH = BK / 8;
  constexpr int RPI = 256 / CH;
  constexpr int NISS = 128 / RPI;
  constexpr int WROW = 64 / CH;
  __shared__ __align__(16) bf16 As[128 * BK];
  __shared__ __align__(16) bf16 Bs[128 * BK];
  const int tid = threadIdx.x;
  const int lane = tid & 63, w = tid >> 6;
  const int g = lane >> 4, l15 = lane & 15;
  const int wm = w >> 1, wn = w & 1;

  const int NT = N >> 7;
  const int nsupN = NT >> 2;
  const int cpx = (int)gridDim.x >> 3;
  const int widx = ((int)blockIdx.x & 7) * cpx + ((int)blockIdx.x >> 3);
  const int s = widx >> 4, r4 = widx & 15;
  const int sm = s / nsupN, sn = s - sm * nsupN;
  const int m0 = (sm * 4 + (r4 & 3)) * 128;
  const int n0 = (sn * 4 + (r4 >> 2)) * 128;

  f32x4 acc[4][4] = {};

  const int srow = tid / CH;
  const int schunk = (tid & (CH - 1)) ^ ((tid / CH) & (CH - 1));
  const char* gA = (const char*)A;
  const char* gB = (const char*)Bt;
  const size_t aOff = ((size_t)(m0 + srow) * K + schunk * 8) * 2;
  const size_t bOff = ((size_t)(n0 + srow) * K + schunk * 8) * 2;

  auto stage = [&](int kt) {
    const size_t kb = (size_t)kt * BK * 2;
#pragma unroll
    for (int i = 0; i < NISS; i++)
      GLOAD_LDS(gA + aOff + (size_t)(i * RPI) * K * 2 + kb,
                &As[(i * RPI + w * WROW) * BK]);
#pragma unroll
    for (int i = 0; i < NISS; i++)
      GLOAD_LDS(gB + bOff + (size_t)(i * RPI) * K * 2 + kb,
                &Bs[(i * RPI + w * WROW) * BK]);
  };

  const int rbA = (wm * 64 + l15) * (2 * BK);
  const int rbB = (wn * 64 + l15) * (2 * BK);

  const int T = K / BK;
  for (int t = 0; t < T; ++t) {
    __syncthreads();  // WAR: all waves done reading previous tile
    stage(t);
    __syncthreads();  // drain; hidden by the other resident block(s)
    const char* pA = (const char*)As;
    const char* pB = (const char*)Bs;
#pragma unroll
    for (int kk = 0; kk < BK / 32; kk++) {
      const int sw = (((kk * 4 + g) ^ (l15 & (CH - 1))) << 4);
      bf16x8 a[4], b[4];
#pragma unroll
      for (int mi = 0; mi < 4; mi++)
        a[mi] = *(const bf16x8*)(pA + rbA + mi * (32 * BK) + sw);
#pragma unroll
      for (int ni = 0; ni < 4; ni++)
        b[ni] = *(const bf16x8*)(pB + rbB + ni * (32 * BK) + sw);
      __builtin_amdgcn_s_setprio(1);
#pragma unroll
      for (int mi = 0; mi < 4; mi++)
#pragma unroll
        for (int ni = 0; ni < 4; ni++)
          acc[mi][ni] = MFMA_BF16(a[mi], b[ni], acc[mi][ni], 0, 0, 0);
      __builtin_amdgcn_s_setprio(0);
    }
  }

  const float qsc = (MODE == 0 && n0 < 1024) ? 0.125f : 1.0f;
  const int row_base = m0 + wm * 64;
  const int col_base = n0 + wn * 64 + l15;
#pragma unroll
  for (int mi = 0; mi < 4; mi++)
#pragma unroll
    for (int ni = 0; ni < 4; ni++) {
      const int c = col_base + ni * 16;
#pragma unroll
      for (int r = 0; r < 4; r++) {
        const int row = row_base + mi * 16 + 4 * g + r;
        const size_t idx = (size_t)row * N + c;
        float v = acc[mi][ni][r];
        if constexpr (MODE == 0) {
          outb[idx] = (bf16)(v * qsc);
        } else if constexpr (MODE == 1) {
          outb[idx] = (bf16)(v + residf[idx]);
        } else if constexpr (MODE == 2) {
          outb[idx] = (bf16)gelu_exact(v);
        } else {
          outf[idx] = v + (float)residb[idx];
        }
      }
    }
}

// ---------------------------------------------------------------- attention
// R18/R21 attention unchanged: 512 thr, BQ=128, paired q-tiles two-pass,
// V^T reg-transposed + K via global_load_lds, single barrier/step,
// permuted-K QK^T, Q pre-scaled, branch-gated causal mask, lazy softmax.
__global__ __launch_bounds__(512, 4) void attn_fwd(const bf16* __restrict__ qkv,
                                                   bf16* __restrict__ O) {
  __shared__ __align__(16) char Kl[2][64 * 128];
  __shared__ __align__(16) char Vt[2][64 * 128];
  const int tid = threadIdx.x;
  const int lane = tid & 63, w = tid >> 6;
  const int g = lane >> 4, l15 = lane & 15;
  const int bh = blockIdx.x;
  const int bx = blockIdx.y;
  const int b = bh >> 4, hh = bh & 15;
  const size_t tokbase = (size_t)b * 2048;

  const bf16* kbase = qkv + tokbase * 3072 + 1024 + hh * 64;
  const bf16* vbase = qkv + tokbase * 3072 + 2048 + hh * 64;
  const int kperm = 8 * (l15 >> 2) + (l15 & 3);

  const int kr8 = tid >> 3, kc = tid & 7;
  const int kswz = (kr8 & 3) | ((kr8 & 8) >> 1);
  const bf16* kSrc = kbase + (size_t)kr8 * 3072 + 8 * (kc ^ kswz);

  const bool vstage = tid < 256;
  const int t2 = tid & 255;
  const int vrg = t2 >> 4, vds = (t2 & 15) * 4;

  union U4 { ushort4 v; u16 a[4]; };
  U4 vr[4];

  auto prefetchV = [&](int k0n) {
    if (vstage) {
#pragma unroll
      for (int i4 = 0; i4 < 4; i4++)
        vr[i4].v = *(const ushort4*)(vbase + (size_t)(k0n + 4 * vrg + i4) * 3072 + vds);
    }
  };
  auto gloadK = [&](int k0n, int buf) {
    GLOAD_LDS(kSrc + (size_t)k0n * 3072, Kl[buf] + w * 1024);
  };

  prefetchV(0);
  gloadK(0, 0);
  int cur = 0;

  for (int half = 0; half < 2; half++) {
    const int xT = half ? (15 - bx) : bx;
    const int q0 = xT * 128;
    const int qw0 = q0 + 16 * w;
    const int qi = qw0 + l15;
    const int kend = q0 + 128;

    const bf16* qptr = qkv + (tokbase + qw0 + l15) * 3072 + hh * 64 + 8 * g;
    const bf16x8 qf0 = *(const bf16x8*)(qptr);
    const bf16x8 qf1 = *(const bf16x8*)(qptr + 32);

    f32x4 ot[4] = {};
    float m_i = -INFINITY, l_i = 0.0f;

    for (int k0 = 0; k0 < kend; k0 += 64) {
      char* Kc = Kl[cur];
      char* Vc = Vt[cur];
      if (vstage) {
#pragma unroll
        for (int dj = 0; dj < 4; dj++) {
          const int d = vds + dj;
          u32 lo = (u32)vr[0].a[dj] | ((u32)vr[1].a[dj] << 16);
          u32 hi2 = (u32)vr[2].a[dj] | ((u32)vr[3].a[dj] << 16);
          const int boff = d * 128 + ((((vrg >> 1) ^ ((d >> 1) & 7)) << 4)) + ((vrg & 1) << 3);
          *(uint2*)(Vc + boff) = make_uint2(lo, hi2);
        }
      }
      __syncthreads();

      const int k0n = (k0 + 64 < kend) ? k0 + 64 : 0;
      prefetchV(k0n);
      gloadK(k0n, cur ^ 1);

      if (k0 <= qw0 + 15) {
        const bool lastT = (k0 + 63 > qw0);
        const int npair = lastT ? (((qw0 + 15 - k0) >> 5) + 1) : 2;

        f32x4 st[4];
#pragma unroll
        for (int ip = 0; ip < 2; ip++)
          if (ip < npair) {
#pragma unroll
            for (int h2 = 0; h2 < 2; h2++) {
              const int kr = 32 * ip + 4 * h2 + kperm;
              const int swzk = (kr & 3) | ((kr & 8) >> 1);
              const char* kro = Kc + kr * 128;
              bf16x8 ka = *(const bf16x8*)(kro + ((g ^ swzk) << 4));
              bf16x8 kb = *(const bf16x8*)(kro + (((g | 4) ^ swzk) << 4));
              f32x4 z = {};
              z = MFMA_BF16(ka, qf0, z, 0, 0, 0);
              st[2 * ip + h2] = MFMA_BF16(kb, qf1, z, 0, 0, 0);
            }
          }

        float p[4][4];
#pragma unroll
        for (int ip = 0; ip < 2; ip++)
          if (ip < npair)
#pragma unroll
            for (int h2 = 0; h2 < 2; h2++)
#pragma unroll
              for (int r = 0; r < 4; r++)
                p[2 * ip + h2][r] = (float)st[2 * ip + h2][r];
        if (lastT) {
#pragma unroll
          for (int ip = 0; ip < 2; ip++)
            if (ip < npair)
#pragma unroll
              for (int h2 = 0; h2 < 2; h2++)
#pragma unroll
                for (int r = 0; r < 4; r++) {
                  const int kk = k0 + 32 * ip + 8 * g + 4 * h2 + r;
                  if (kk > qi) p[2 * ip + h2][r] = -INFINITY;
                }
        }
        float mt = -INFINITY;
#pragma unroll
        for (int ip = 0; ip < 2; ip++)
          if (ip < npair)
#pragma unroll
            for (int h2 = 0; h2 < 2; h2++)
#pragma unroll
              for (int r = 0; r < 4; r++) mt = fmaxf(mt, p[2 * ip + h2][r]);

        if (!__all(mt - m_i <= 8.0f)) {
          mt = fmaxf(mt, __shfl_xor(mt, 16, 64));
          mt = fmaxf(mt, __shfl_xor(mt, 32, 64));
          const float m_new = fmaxf(m_i, mt);
          const float alpha = __expf(m_i - m_new);
          l_i *= alpha;
#pragma unroll
          for (int dt = 0; dt < 4; dt++)
#pragma unroll
            for (int r = 0; r < 4; r++) ot[dt][r] *= alpha;
          m_i = m_new;
        }
        float sum = 0.0f;
#pragma unroll
        for (int ip = 0; ip < 2; ip++)
          if (ip < npair) {
#pragma unroll
            for (int h2 = 0; h2 < 2; h2++)
#pragma unroll
              for (int r = 0; r < 4; r++) {
                float e = __expf(p[2 * ip + h2][r] - m_i);
                p[2 * ip + h2][r] = e;
                sum += e;
              }
          }
        l_i += sum;

#pragma unroll
        for (int ip = 0; ip < 2; ip++)
          if (ip < npair) {
            bf16x8 pf;
#pragma unroll
            for (int h2 = 0; h2 < 2; h2++)
#pragma unroll
              for (int r = 0; r < 4; r++) pf[4 * h2 + r] = (bf16)p[2 * ip + h2][r];
#pragma unroll
            for (int dt = 0; dt < 4; dt++) {
              const bf16x8 vf = *(const bf16x8*)(
                  Vc + (dt * 16 + l15) * 128 + (((4 * ip + g) ^ (l15 >> 1)) << 4));
              ot[dt] = MFMA_BF16(vf, pf, ot[dt], 0, 0, 0);
            }
          }
      }
      cur ^= 1;
    }

    l_i += __shfl_xor(l_i, 16, 64);
    l_i += __shfl_xor(l_i, 32, 64);
    const float inv = 1.0f / l_i;
    bf16* obase = O + (tokbase + qw0 + l15) * 1024 + hh * 64;
#pragma unroll
    for (int dt = 0; dt < 4; dt++) {
      bf16x4 ov;
#pragma unroll
      for (int r = 0; r < 4; r++) ov[r] = (bf16)(ot[dt][r] * inv);
      *(bf16x4*)(obase + dt * 16 + 4 * g) = ov;
    }
  }
}

// ---------------------------------------------------------------- launch
extern "C" void kernel_launch(void* const* d_in, const int* in_sizes, int n_in,
                              void* d_out, int out_size, void* d_ws, size_t ws_size,
                              hipStream_t stream) {
  const float* x = (const float*)d_in[0];
  const float* w_qkv = (const float*)d_in[1];
  const float* w_out = (const float*)d_in[2];
  const float* w_ff1 = (const float*)d_in[3];
  const float* w_ff2 = (const float*)d_in[4];
  float* out = (float*)d_out;

  char* ws = (char*)d_ws;
  size_t off = 0;
  auto alloc = [&](size_t bytes) {
    void* p = ws + off;
    off += (bytes + 255) & ~(size_t)255;
    return p;
  };
  const size_t M = 8192;
  bf16* X16   = (bf16*)alloc(M * 1024 * 2);
  bf16* WqkvT = (bf16*)alloc(3072ull * 1024 * 2);
  bf16* WoutT = (bf16*)alloc(1024ull * 1024 * 2);
  bf16* Wff1T = (bf16*)alloc(4096ull * 1024 * 2);
  bf16* Wff2T = (bf16*)alloc(1024ull * 4096 * 2);
  bf16* QKV   = (bf16*)alloc(M * 3072 * 2);
  bf16* Obuf  = (bf16*)alloc(M * 1024 * 2);
  bf16* x1b   = (bf16*)alloc(M * 1024 * 2);
  bf16* Hbuf  = (bf16*)alloc(M * 4096 * 2);

  cvt_f32_bf16<<<8192, 256, 0, stream>>>(x, X16, 8192 * 1024);
  transpose_w<<<dim3(3072 / 32, 1024 / 32), 256, 0, stream>>>(w_qkv, WqkvT, 1024, 3072);
  transpose_w<<<dim3(1024 / 32, 1024 / 32), 256, 0, stream>>>(w_out, WoutT, 1024, 1024);
  transpose_w<<<dim3(4096 / 32, 1024 / 32), 256, 0, stream>>>(w_ff1, Wff1T, 1024, 4096);
  transpose_w<<<dim3(1024 / 32, 4096 / 32), 256, 0, stream>>>(w_ff2, Wff2T, 4096, 1024);

  gemm_bt<0, 128><<<64 * 24, 256, 0, stream>>>(X16, WqkvT, QKV, nullptr, nullptr, nullptr, 1024, 3072);
  attn_fwd<<<dim3(64, 8), 512, 0, stream>>>(QKV, Obuf);
  gemm_bt<1, 128><<<64 * 8, 256, 0, stream>>>(Obuf, WoutT, x1b, nullptr, x, nullptr, 1024, 1024);
  gemm_bt<2, 128><<<64 * 32, 256, 0, stream>>>(x1b, Wff1T, Hbuf, nullptr, nullptr, nullptr, 1024, 4096);
  gemm_bt<3, 128><<<64 * 8, 256, 0, stream>>>(Hbuf, Wff2T, nullptr, out, nullptr, x1b, 4096, 1024);
}

// Round 24
// 322.131 us; speedup vs baseline: 1.0212x; 1.0212x over previous
//
#include <hip/hip_runtime.h>

typedef __bf16 bf16;
typedef __bf16 bf16x8 __attribute__((ext_vector_type(8)));
typedef __bf16 bf16x4 __attribute__((ext_vector_type(4)));
typedef float f32x4 __attribute__((ext_vector_type(4)));
typedef unsigned int u32;
typedef unsigned short u16;

#define MFMA_BF16 __builtin_amdgcn_mfma_f32_16x16x32_bf16

#define GLOAD_LDS(g, l)                                        \
  __builtin_amdgcn_global_load_lds(                            \
      (__attribute__((address_space(1))) void*)(g),            \
      (__attribute__((address_space(3))) void*)(l), 16, 0, 0)

// ---------------------------------------------------------------- utilities
__global__ void cvt_f32_bf16(const float* __restrict__ in, bf16* __restrict__ out, int n) {
  int i = (blockIdx.x * blockDim.x + threadIdx.x) * 4;
  if (i >= n) return;
  float4 v = *(const float4*)(in + i);
  bf16x4 o;
  o[0] = (bf16)v.x; o[1] = (bf16)v.y; o[2] = (bf16)v.z; o[3] = (bf16)v.w;
  *(bf16x4*)(out + i) = o;
}

// W [K][N] fp32 -> Wt [N][K] bf16
__global__ void transpose_w(const float* __restrict__ w, bf16* __restrict__ wt, int K, int N) {
  __shared__ float tile[32][33];
  int n0 = blockIdx.x * 32, k0 = blockIdx.y * 32;
  int t = threadIdx.x;
  int c = t & 31, r = t >> 5;
#pragma unroll
  for (int i = 0; i < 4; i++)
    tile[r + i * 8][c] = w[(size_t)(k0 + r + i * 8) * N + n0 + c];
  __syncthreads();
#pragma unroll
  for (int i = 0; i < 4; i++)
    wt[(size_t)(n0 + r + i * 8) * K + k0 + c] = (bf16)tile[c][r + i * 8];
}

__device__ inline float gelu_exact(float x) {
  return 0.5f * x * (1.0f + erff(x * 0.70710678118654752f));
}

// ---------------------------------------------------------------- GEMM
// R22 config (best measured, 321.4us): BK is K-depth-conditional —
// BK=64 (32KB LDS, 3 blocks/CU) for K=1024 (qkv/ff1: only 8 BK128-steps
// would leave the drain tail uncovered at 2 blocks — R23 regression);
// BK=128 (64KB LDS, 2 blocks/CU) for K=4096/short-grid (proj/ff2), halving
// barrier/drain events. 128x128 tile, 4 waves 2Mx2N, wave tile 64x64,
// acc[4][4], single-buffered LDS, 2 barriers/K-step, 0-conflict involution
// swizzle, supertile XCD L2 order. MODE 0 pre-scales Q cols by 0.125.
// MODE 1 residual now reads bf16 (X16) — halves proj residual fetch.
template <int MODE, int BK>
__global__ __launch_bounds__(256, (BK == 128) ? 2 : 3) void gemm_bt(
    const bf16* __restrict__ A, const bf16* __restrict__ Bt,
    bf16* __restrict__ outb, float* __restrict__ outf,
    const bf16* __restrict__ residb, int K, int N) {
  constexpr int CH = BK / 8;
  constexpr int RPI = 256 / CH;
  constexpr int NISS = 128 / RPI;
  constexpr int WROW = 64 / CH;
  __shared__ __align__(16) bf16 As[128 * BK];
  __shared__ __align__(16) bf16 Bs[128 * BK];
  const int tid = threadIdx.x;
  const int lane = tid & 63, w = tid >> 6;
  const int g = lane >> 4, l15 = lane & 15;
  const int wm = w >> 1, wn = w & 1;

  const int NT = N >> 7;
  const int nsupN = NT >> 2;
  const int cpx = (int)gridDim.x >> 3;
  const int widx = ((int)blockIdx.x & 7) * cpx + ((int)blockIdx.x >> 3);
  const int s = widx >> 4, r4 = widx & 15;
  const int sm = s / nsupN, sn = s - sm * nsupN;
  const int m0 = (sm * 4 + (r4 & 3)) * 128;
  const int n0 = (sn * 4 + (r4 >> 2)) * 128;

  f32x4 acc[4][4] = {};

  const int srow = tid / CH;
  const int schunk = (tid & (CH - 1)) ^ ((tid / CH) & (CH - 1));
  const char* gA = (const char*)A;
  const char* gB = (const char*)Bt;
  const size_t aOff = ((size_t)(m0 + srow) * K + schunk * 8) * 2;
  const size_t bOff = ((size_t)(n0 + srow) * K + schunk * 8) * 2;

  auto stage = [&](int kt) {
    const size_t kb = (size_t)kt * BK * 2;
#pragma unroll
    for (int i = 0; i < NISS; i++)
      GLOAD_LDS(gA + aOff + (size_t)(i * RPI) * K * 2 + kb,
                &As[(i * RPI + w * WROW) * BK]);
#pragma unroll
    for (int i = 0; i < NISS; i++)
      GLOAD_LDS(gB + bOff + (size_t)(i * RPI) * K * 2 + kb,
                &Bs[(i * RPI + w * WROW) * BK]);
  };

  const int rbA = (wm * 64 + l15) * (2 * BK);
  const int rbB = (wn * 64 + l15) * (2 * BK);

  const int T = K / BK;
  for (int t = 0; t < T; ++t) {
    __syncthreads();  // WAR: all waves done reading previous tile
    stage(t);
    __syncthreads();  // drain; hidden by the other resident block(s)
    const char* pA = (const char*)As;
    const char* pB = (const char*)Bs;
#pragma unroll
    for (int kk = 0; kk < BK / 32; kk++) {
      const int sw = (((kk * 4 + g) ^ (l15 & (CH - 1))) << 4);
      bf16x8 a[4], b[4];
#pragma unroll
      for (int mi = 0; mi < 4; mi++)
        a[mi] = *(const bf16x8*)(pA + rbA + mi * (32 * BK) + sw);
#pragma unroll
      for (int ni = 0; ni < 4; ni++)
        b[ni] = *(const bf16x8*)(pB + rbB + ni * (32 * BK) + sw);
      __builtin_amdgcn_s_setprio(1);
#pragma unroll
      for (int mi = 0; mi < 4; mi++)
#pragma unroll
        for (int ni = 0; ni < 4; ni++)
          acc[mi][ni] = MFMA_BF16(a[mi], b[ni], acc[mi][ni], 0, 0, 0);
      __builtin_amdgcn_s_setprio(0);
    }
  }

  const float qsc = (MODE == 0 && n0 < 1024) ? 0.125f : 1.0f;
  const int row_base = m0 + wm * 64;
  const int col_base = n0 + wn * 64 + l15;
#pragma unroll
  for (int mi = 0; mi < 4; mi++)
#pragma unroll
    for (int ni = 0; ni < 4; ni++) {
      const int c = col_base + ni * 16;
#pragma unroll
      for (int r = 0; r < 4; r++) {
        const int row = row_base + mi * 16 + 4 * g + r;
        const size_t idx = (size_t)row * N + c;
        float v = acc[mi][ni][r];
        if constexpr (MODE == 0) {
          outb[idx] = (bf16)(v * qsc);
        } else if constexpr (MODE == 1) {
          outb[idx] = (bf16)(v + (float)residb[idx]);
        } else if constexpr (MODE == 2) {
          outb[idx] = (bf16)gelu_exact(v);
        } else {
          outf[idx] = v + (float)residb[idx];
        }
      }
    }
}

// ---------------------------------------------------------------- attention
// R18/R21 attention unchanged: 512 thr, BQ=128, paired q-tiles two-pass,
// V^T reg-transposed + K via global_load_lds, single barrier/step,
// permuted-K QK^T, Q pre-scaled, branch-gated causal mask, lazy softmax.
__global__ __launch_bounds__(512, 4) void attn_fwd(const bf16* __restrict__ qkv,
                                                   bf16* __restrict__ O) {
  __shared__ __align__(16) char Kl[2][64 * 128];
  __shared__ __align__(16) char Vt[2][64 * 128];
  const int tid = threadIdx.x;
  const int lane = tid & 63, w = tid >> 6;
  const int g = lane >> 4, l15 = lane & 15;
  const int bh = blockIdx.x;
  const int bx = blockIdx.y;
  const int b = bh >> 4, hh = bh & 15;
  const size_t tokbase = (size_t)b * 2048;

  const bf16* kbase = qkv + tokbase * 3072 + 1024 + hh * 64;
  const bf16* vbase = qkv + tokbase * 3072 + 2048 + hh * 64;
  const int kperm = 8 * (l15 >> 2) + (l15 & 3);

  const int kr8 = tid >> 3, kc = tid & 7;
  const int kswz = (kr8 & 3) | ((kr8 & 8) >> 1);
  const bf16* kSrc = kbase + (size_t)kr8 * 3072 + 8 * (kc ^ kswz);

  const bool vstage = tid < 256;
  const int t2 = tid & 255;
  const int vrg = t2 >> 4, vds = (t2 & 15) * 4;

  union U4 { ushort4 v; u16 a[4]; };
  U4 vr[4];

  auto prefetchV = [&](int k0n) {
    if (vstage) {
#pragma unroll
      for (int i4 = 0; i4 < 4; i4++)
        vr[i4].v = *(const ushort4*)(vbase + (size_t)(k0n + 4 * vrg + i4) * 3072 + vds);
    }
  };
  auto gloadK = [&](int k0n, int buf) {
    GLOAD_LDS(kSrc + (size_t)k0n * 3072, Kl[buf] + w * 1024);
  };

  prefetchV(0);
  gloadK(0, 0);
  int cur = 0;

  for (int half = 0; half < 2; half++) {
    const int xT = half ? (15 - bx) : bx;
    const int q0 = xT * 128;
    const int qw0 = q0 + 16 * w;
    const int qi = qw0 + l15;
    const int kend = q0 + 128;

    const bf16* qptr = qkv + (tokbase + qw0 + l15) * 3072 + hh * 64 + 8 * g;
    const bf16x8 qf0 = *(const bf16x8*)(qptr);
    const bf16x8 qf1 = *(const bf16x8*)(qptr + 32);

    f32x4 ot[4] = {};
    float m_i = -INFINITY, l_i = 0.0f;

    for (int k0 = 0; k0 < kend; k0 += 64) {
      char* Kc = Kl[cur];
      char* Vc = Vt[cur];
      if (vstage) {
#pragma unroll
        for (int dj = 0; dj < 4; dj++) {
          const int d = vds + dj;
          u32 lo = (u32)vr[0].a[dj] | ((u32)vr[1].a[dj] << 16);
          u32 hi2 = (u32)vr[2].a[dj] | ((u32)vr[3].a[dj] << 16);
          const int boff = d * 128 + ((((vrg >> 1) ^ ((d >> 1) & 7)) << 4)) + ((vrg & 1) << 3);
          *(uint2*)(Vc + boff) = make_uint2(lo, hi2);
        }
      }
      __syncthreads();

      const int k0n = (k0 + 64 < kend) ? k0 + 64 : 0;
      prefetchV(k0n);
      gloadK(k0n, cur ^ 1);

      if (k0 <= qw0 + 15) {
        const bool lastT = (k0 + 63 > qw0);
        const int npair = lastT ? (((qw0 + 15 - k0) >> 5) + 1) : 2;

        f32x4 st[4];
#pragma unroll
        for (int ip = 0; ip < 2; ip++)
          if (ip < npair) {
#pragma unroll
            for (int h2 = 0; h2 < 2; h2++) {
              const int kr = 32 * ip + 4 * h2 + kperm;
              const int swzk = (kr & 3) | ((kr & 8) >> 1);
              const char* kro = Kc + kr * 128;
              bf16x8 ka = *(const bf16x8*)(kro + ((g ^ swzk) << 4));
              bf16x8 kb = *(const bf16x8*)(kro + (((g | 4) ^ swzk) << 4));
              f32x4 z = {};
              z = MFMA_BF16(ka, qf0, z, 0, 0, 0);
              st[2 * ip + h2] = MFMA_BF16(kb, qf1, z, 0, 0, 0);
            }
          }

        float p[4][4];
#pragma unroll
        for (int ip = 0; ip < 2; ip++)
          if (ip < npair)
#pragma unroll
            for (int h2 = 0; h2 < 2; h2++)
#pragma unroll
              for (int r = 0; r < 4; r++)
                p[2 * ip + h2][r] = (float)st[2 * ip + h2][r];
        if (lastT) {
#pragma unroll
          for (int ip = 0; ip < 2; ip++)
            if (ip < npair)
#pragma unroll
              for (int h2 = 0; h2 < 2; h2++)
#pragma unroll
                for (int r = 0; r < 4; r++) {
                  const int kk = k0 + 32 * ip + 8 * g + 4 * h2 + r;
                  if (kk > qi) p[2 * ip + h2][r] = -INFINITY;
                }
        }
        float mt = -INFINITY;
#pragma unroll
        for (int ip = 0; ip < 2; ip++)
          if (ip < npair)
#pragma unroll
            for (int h2 = 0; h2 < 2; h2++)
#pragma unroll
              for (int r = 0; r < 4; r++) mt = fmaxf(mt, p[2 * ip + h2][r]);

        if (!__all(mt - m_i <= 8.0f)) {
          mt = fmaxf(mt, __shfl_xor(mt, 16, 64));
          mt = fmaxf(mt, __shfl_xor(mt, 32, 64));
          const float m_new = fmaxf(m_i, mt);
          const float alpha = __expf(m_i - m_new);
          l_i *= alpha;
#pragma unroll
          for (int dt = 0; dt < 4; dt++)
#pragma unroll
            for (int r = 0; r < 4; r++) ot[dt][r] *= alpha;
          m_i = m_new;
        }
        float sum = 0.0f;
#pragma unroll
        for (int ip = 0; ip < 2; ip++)
          if (ip < npair) {
#pragma unroll
            for (int h2 = 0; h2 < 2; h2++)
#pragma unroll
              for (int r = 0; r < 4; r++) {
                float e = __expf(p[2 * ip + h2][r] - m_i);
                p[2 * ip + h2][r] = e;
                sum += e;
              }
          }
        l_i += sum;

#pragma unroll
        for (int ip = 0; ip < 2; ip++)
          if (ip < npair) {
            bf16x8 pf;
#pragma unroll
            for (int h2 = 0; h2 < 2; h2++)
#pragma unroll
              for (int r = 0; r < 4; r++) pf[4 * h2 + r] = (bf16)p[2 * ip + h2][r];
#pragma unroll
            for (int dt = 0; dt < 4; dt++) {
              const bf16x8 vf = *(const bf16x8*)(
                  Vc + (dt * 16 + l15) * 128 + (((4 * ip + g) ^ (l15 >> 1)) << 4));
              ot[dt] = MFMA_BF16(vf, pf, ot[dt], 0, 0, 0);
            }
          }
      }
      cur ^= 1;
    }

    l_i += __shfl_xor(l_i, 16, 64);
    l_i += __shfl_xor(l_i, 32, 64);
    const float inv = 1.0f / l_i;
    bf16* obase = O + (tokbase + qw0 + l15) * 1024 + hh * 64;
#pragma unroll
    for (int dt = 0; dt < 4; dt++) {
      bf16x4 ov;
#pragma unroll
      for (int r = 0; r < 4; r++) ov[r] = (bf16)(ot[dt][r] * inv);
      *(bf16x4*)(obase + dt * 16 + 4 * g) = ov;
    }
  }
}

// ---------------------------------------------------------------- launch
extern "C" void kernel_launch(void* const* d_in, const int* in_sizes, int n_in,
                              void* d_out, int out_size, void* d_ws, size_t ws_size,
                              hipStream_t stream) {
  const float* x = (const float*)d_in[0];
  const float* w_qkv = (const float*)d_in[1];
  const float* w_out = (const float*)d_in[2];
  const float* w_ff1 = (const float*)d_in[3];
  const float* w_ff2 = (const float*)d_in[4];
  float* out = (float*)d_out;

  char* ws = (char*)d_ws;
  size_t off = 0;
  auto alloc = [&](size_t bytes) {
    void* p = ws + off;
    off += (bytes + 255) & ~(size_t)255;
    return p;
  };
  const size_t M = 8192;
  bf16* X16   = (bf16*)alloc(M * 1024 * 2);
  bf16* WqkvT = (bf16*)alloc(3072ull * 1024 * 2);
  bf16* WoutT = (bf16*)alloc(1024ull * 1024 * 2);
  bf16* Wff1T = (bf16*)alloc(4096ull * 1024 * 2);
  bf16* Wff2T = (bf16*)alloc(1024ull * 4096 * 2);
  bf16* QKV   = (bf16*)alloc(M * 3072 * 2);
  bf16* Obuf  = (bf16*)alloc(M * 1024 * 2);
  bf16* x1b   = (bf16*)alloc(M * 1024 * 2);
  bf16* Hbuf  = (bf16*)alloc(M * 4096 * 2);

  cvt_f32_bf16<<<8192, 256, 0, stream>>>(x, X16, 8192 * 1024);
  transpose_w<<<dim3(3072 / 32, 1024 / 32), 256, 0, stream>>>(w_qkv, WqkvT, 1024, 3072);
  transpose_w<<<dim3(1024 / 32, 1024 / 32), 256, 0, stream>>>(w_out, WoutT, 1024, 1024);
  transpose_w<<<dim3(4096 / 32, 1024 / 32), 256, 0, stream>>>(w_ff1, Wff1T, 1024, 4096);
  transpose_w<<<dim3(1024 / 32, 4096 / 32), 256, 0, stream>>>(w_ff2, Wff2T, 4096, 1024);

  gemm_bt<0, 64><<<64 * 24, 256, 0, stream>>>(X16, WqkvT, QKV, nullptr, nullptr, 1024, 3072);
  attn_fwd<<<dim3(64, 8), 512, 0, stream>>>(QKV, Obuf);
  gemm_bt<1, 128><<<64 * 8, 256, 0, stream>>>(Obuf, WoutT, x1b, nullptr, X16, 1024, 1024);
  gemm_bt<2, 64><<<64 * 32, 256, 0, stream>>>(x1b, Wff1T, Hbuf, nullptr, nullptr, 1024, 4096);
  gemm_bt<3, 128><<<64 * 8, 256, 0, stream>>>(Hbuf, Wff2T, nullptr, out, x1b, 4096, 1024);
}

// Round 25
// 318.819 us; speedup vs baseline: 1.0318x; 1.0104x over previous
//
#include <hip/hip_runtime.h>

typedef __bf16 bf16;
typedef __bf16 bf16x8 __attribute__((ext_vector_type(8)));
typedef __bf16 bf16x4 __attribute__((ext_vector_type(4)));
typedef float f32x4 __attribute__((ext_vector_type(4)));
typedef unsigned int u32;
typedef unsigned short u16;

#define MFMA_BF16 __builtin_amdgcn_mfma_f32_16x16x32_bf16

#define GLOAD_LDS(g, l)                                        \
  __builtin_amdgcn_global_load_lds(                            \
      (__attribute__((address_space(1))) void*)(g),            \
      (__attribute__((address_space(3))) void*)(l), 16, 0, 0)

// ---------------------------------------------------------------- utilities
__global__ void cvt_f32_bf16(const float* __restrict__ in, bf16* __restrict__ out, int n) {
  int i = (blockIdx.x * blockDim.x + threadIdx.x) * 4;
  if (i >= n) return;
  float4 v = *(const float4*)(in + i);
  bf16x4 o;
  o[0] = (bf16)v.x; o[1] = (bf16)v.y; o[2] = (bf16)v.z; o[3] = (bf16)v.w;
  *(bf16x4*)(out + i) = o;
}

// W [K][N] fp32 -> Wt [N][K] bf16
__global__ void transpose_w(const float* __restrict__ w, bf16* __restrict__ wt, int K, int N) {
  __shared__ float tile[32][33];
  int n0 = blockIdx.x * 32, k0 = blockIdx.y * 32;
  int t = threadIdx.x;
  int c = t & 31, r = t >> 5;
#pragma unroll
  for (int i = 0; i < 4; i++)
    tile[r + i * 8][c] = w[(size_t)(k0 + r + i * 8) * N + n0 + c];
  __syncthreads();
#pragma unroll
  for (int i = 0; i < 4; i++)
    wt[(size_t)(n0 + r + i * 8) * K + k0 + c] = (bf16)tile[c][r + i * 8];
}

// tanh-form GELU via sigmoid: gelu(x) ~= x * sigmoid(1.5957288x + 0.0713548x^3)
// max |dev| from exact-erf GELU ~ 3e-4 << bf16 rounding of the outputs.
// 1 transcendental (v_exp_f32) + ~6 VALU vs ~25+ for ocml erff.
__device__ inline float gelu_fast(float x) {
  float y = x * (1.59577f + 0.0713548f * x * x);
  return x / (1.0f + __expf(-y));
}

// ---------------------------------------------------------------- GEMM
// R22/R24 config (best measured): BK K-depth-conditional — BK=64 (32KB LDS,
// 3 blocks/CU) for K=1024 (qkv/ff1); BK=128 (64KB LDS, 2 blocks/CU) for
// K=4096/short-grid (proj/ff2). 128x128 tile, 4 waves 2Mx2N, wave tile
// 64x64, acc[4][4], single-buffered LDS, 2 barriers/K-step, 0-conflict
// involution swizzle, supertile XCD L2 order. MODE 0 pre-scales Q cols
// by 0.125. MODE 2 epilogue now uses gelu_fast (VALU trim).
template <int MODE, int BK>
__global__ __launch_bounds__(256, (BK == 128) ? 2 : 3) void gemm_bt(
    const bf16* __restrict__ A, const bf16* __restrict__ Bt,
    bf16* __restrict__ outb, float* __restrict__ outf,
    const bf16* __restrict__ residb, int K, int N) {
  constexpr int CH = BK / 8;
  constexpr int RPI = 256 / CH;
  constexpr int NISS = 128 / RPI;
  constexpr int WROW = 64 / CH;
  __shared__ __align__(16) bf16 As[128 * BK];
  __shared__ __align__(16) bf16 Bs[128 * BK];
  const int tid = threadIdx.x;
  const int lane = tid & 63, w = tid >> 6;
  const int g = lane >> 4, l15 = lane & 15;
  const int wm = w >> 1, wn = w & 1;

  const int NT = N >> 7;
  const int nsupN = NT >> 2;
  const int cpx = (int)gridDim.x >> 3;
  const int widx = ((int)blockIdx.x & 7) * cpx + ((int)blockIdx.x >> 3);
  const int s = widx >> 4, r4 = widx & 15;
  const int sm = s / nsupN, sn = s - sm * nsupN;
  const int m0 = (sm * 4 + (r4 & 3)) * 128;
  const int n0 = (sn * 4 + (r4 >> 2)) * 128;

  f32x4 acc[4][4] = {};

  const int srow = tid / CH;
  const int schunk = (tid & (CH - 1)) ^ ((tid / CH) & (CH - 1));
  const char* gA = (const char*)A;
  const char* gB = (const char*)Bt;
  const size_t aOff = ((size_t)(m0 + srow) * K + schunk * 8) * 2;
  const size_t bOff = ((size_t)(n0 + srow) * K + schunk * 8) * 2;

  auto stage = [&](int kt) {
    const size_t kb = (size_t)kt * BK * 2;
#pragma unroll
    for (int i = 0; i < NISS; i++)
      GLOAD_LDS(gA + aOff + (size_t)(i * RPI) * K * 2 + kb,
                &As[(i * RPI + w * WROW) * BK]);
#pragma unroll
    for (int i = 0; i < NISS; i++)
      GLOAD_LDS(gB + bOff + (size_t)(i * RPI) * K * 2 + kb,
                &Bs[(i * RPI + w * WROW) * BK]);
  };

  const int rbA = (wm * 64 + l15) * (2 * BK);
  const int rbB = (wn * 64 + l15) * (2 * BK);

  const int T = K / BK;
  for (int t = 0; t < T; ++t) {
    __syncthreads();  // WAR: all waves done reading previous tile
    stage(t);
    __syncthreads();  // drain; hidden by the other resident block(s)
    const char* pA = (const char*)As;
    const char* pB = (const char*)Bs;
#pragma unroll
    for (int kk = 0; kk < BK / 32; kk++) {
      const int sw = (((kk * 4 + g) ^ (l15 & (CH - 1))) << 4);
      bf16x8 a[4], b[4];
#pragma unroll
      for (int mi = 0; mi < 4; mi++)
        a[mi] = *(const bf16x8*)(pA + rbA + mi * (32 * BK) + sw);
#pragma unroll
      for (int ni = 0; ni < 4; ni++)
        b[ni] = *(const bf16x8*)(pB + rbB + ni * (32 * BK) + sw);
      __builtin_amdgcn_s_setprio(1);
#pragma unroll
      for (int mi = 0; mi < 4; mi++)
#pragma unroll
        for (int ni = 0; ni < 4; ni++)
          acc[mi][ni] = MFMA_BF16(a[mi], b[ni], acc[mi][ni], 0, 0, 0);
      __builtin_amdgcn_s_setprio(0);
    }
  }

  const float qsc = (MODE == 0 && n0 < 1024) ? 0.125f : 1.0f;
  const int row_base = m0 + wm * 64;
  const int col_base = n0 + wn * 64 + l15;
#pragma unroll
  for (int mi = 0; mi < 4; mi++)
#pragma unroll
    for (int ni = 0; ni < 4; ni++) {
      const int c = col_base + ni * 16;
#pragma unroll
      for (int r = 0; r < 4; r++) {
        const int row = row_base + mi * 16 + 4 * g + r;
        const size_t idx = (size_t)row * N + c;
        float v = acc[mi][ni][r];
        if constexpr (MODE == 0) {
          outb[idx] = (bf16)(v * qsc);
        } else if constexpr (MODE == 1) {
          outb[idx] = (bf16)(v + (float)residb[idx]);
        } else if constexpr (MODE == 2) {
          outb[idx] = (bf16)gelu_fast(v);
        } else {
          outf[idx] = v + (float)residb[idx];
        }
      }
    }
}

// ---------------------------------------------------------------- attention
// R18/R21 attention unchanged: 512 thr, BQ=128, paired q-tiles two-pass,
// V^T reg-transposed + K via global_load_lds, single barrier/step,
// permuted-K QK^T, Q pre-scaled, branch-gated causal mask, lazy softmax.
__global__ __launch_bounds__(512, 4) void attn_fwd(const bf16* __restrict__ qkv,
                                                   bf16* __restrict__ O) {
  __shared__ __align__(16) char Kl[2][64 * 128];
  __shared__ __align__(16) char Vt[2][64 * 128];
  const int tid = threadIdx.x;
  const int lane = tid & 63, w = tid >> 6;
  const int g = lane >> 4, l15 = lane & 15;
  const int bh = blockIdx.x;
  const int bx = blockIdx.y;
  const int b = bh >> 4, hh = bh & 15;
  const size_t tokbase = (size_t)b * 2048;

  const bf16* kbase = qkv + tokbase * 3072 + 1024 + hh * 64;
  const bf16* vbase = qkv + tokbase * 3072 + 2048 + hh * 64;
  const int kperm = 8 * (l15 >> 2) + (l15 & 3);

  const int kr8 = tid >> 3, kc = tid & 7;
  const int kswz = (kr8 & 3) | ((kr8 & 8) >> 1);
  const bf16* kSrc = kbase + (size_t)kr8 * 3072 + 8 * (kc ^ kswz);

  const bool vstage = tid < 256;
  const int t2 = tid & 255;
  const int vrg = t2 >> 4, vds = (t2 & 15) * 4;

  union U4 { ushort4 v; u16 a[4]; };
  U4 vr[4];

  auto prefetchV = [&](int k0n) {
    if (vstage) {
#pragma unroll
      for (int i4 = 0; i4 < 4; i4++)
        vr[i4].v = *(const ushort4*)(vbase + (size_t)(k0n + 4 * vrg + i4) * 3072 + vds);
    }
  };
  auto gloadK = [&](int k0n, int buf) {
    GLOAD_LDS(kSrc + (size_t)k0n * 3072, Kl[buf] + w * 1024);
  };

  prefetchV(0);
  gloadK(0, 0);
  int cur = 0;

  for (int half = 0; half < 2; half++) {
    const int xT = half ? (15 - bx) : bx;
    const int q0 = xT * 128;
    const int qw0 = q0 + 16 * w;
    const int qi = qw0 + l15;
    const int kend = q0 + 128;

    const bf16* qptr = qkv + (tokbase + qw0 + l15) * 3072 + hh * 64 + 8 * g;
    const bf16x8 qf0 = *(const bf16x8*)(qptr);
    const bf16x8 qf1 = *(const bf16x8*)(qptr + 32);

    f32x4 ot[4] = {};
    float m_i = -INFINITY, l_i = 0.0f;

    for (int k0 = 0; k0 < kend; k0 += 64) {
      char* Kc = Kl[cur];
      char* Vc = Vt[cur];
      if (vstage) {
#pragma unroll
        for (int dj = 0; dj < 4; dj++) {
          const int d = vds + dj;
          u32 lo = (u32)vr[0].a[dj] | ((u32)vr[1].a[dj] << 16);
          u32 hi2 = (u32)vr[2].a[dj] | ((u32)vr[3].a[dj] << 16);
          const int boff = d * 128 + ((((vrg >> 1) ^ ((d >> 1) & 7)) << 4)) + ((vrg & 1) << 3);
          *(uint2*)(Vc + boff) = make_uint2(lo, hi2);
        }
      }
      __syncthreads();

      const int k0n = (k0 + 64 < kend) ? k0 + 64 : 0;
      prefetchV(k0n);
      gloadK(k0n, cur ^ 1);

      if (k0 <= qw0 + 15) {
        const bool lastT = (k0 + 63 > qw0);
        const int npair = lastT ? (((qw0 + 15 - k0) >> 5) + 1) : 2;

        f32x4 st[4];
#pragma unroll
        for (int ip = 0; ip < 2; ip++)
          if (ip < npair) {
#pragma unroll
            for (int h2 = 0; h2 < 2; h2++) {
              const int kr = 32 * ip + 4 * h2 + kperm;
              const int swzk = (kr & 3) | ((kr & 8) >> 1);
              const char* kro = Kc + kr * 128;
              bf16x8 ka = *(const bf16x8*)(kro + ((g ^ swzk) << 4));
              bf16x8 kb = *(const bf16x8*)(kro + (((g | 4) ^ swzk) << 4));
              f32x4 z = {};
              z = MFMA_BF16(ka, qf0, z, 0, 0, 0);
              st[2 * ip + h2] = MFMA_BF16(kb, qf1, z, 0, 0, 0);
            }
          }

        float p[4][4];
#pragma unroll
        for (int ip = 0; ip < 2; ip++)
          if (ip < npair)
#pragma unroll
            for (int h2 = 0; h2 < 2; h2++)
#pragma unroll
              for (int r = 0; r < 4; r++)
                p[2 * ip + h2][r] = (float)st[2 * ip + h2][r];
        if (lastT) {
#pragma unroll
          for (int ip = 0; ip < 2; ip++)
            if (ip < npair)
#pragma unroll
              for (int h2 = 0; h2 < 2; h2++)
#pragma unroll
                for (int r = 0; r < 4; r++) {
                  const int kk = k0 + 32 * ip + 8 * g + 4 * h2 + r;
                  if (kk > qi) p[2 * ip + h2][r] = -INFINITY;
                }
        }
        float mt = -INFINITY;
#pragma unroll
        for (int ip = 0; ip < 2; ip++)
          if (ip < npair)
#pragma unroll
            for (int h2 = 0; h2 < 2; h2++)
#pragma unroll
              for (int r = 0; r < 4; r++) mt = fmaxf(mt, p[2 * ip + h2][r]);

        if (!__all(mt - m_i <= 8.0f)) {
          mt = fmaxf(mt, __shfl_xor(mt, 16, 64));
          mt = fmaxf(mt, __shfl_xor(mt, 32, 64));
          const float m_new = fmaxf(m_i, mt);
          const float alpha = __expf(m_i - m_new);
          l_i *= alpha;
#pragma unroll
          for (int dt = 0; dt < 4; dt++)
#pragma unroll
            for (int r = 0; r < 4; r++) ot[dt][r] *= alpha;
          m_i = m_new;
        }
        float sum = 0.0f;
#pragma unroll
        for (int ip = 0; ip < 2; ip++)
          if (ip < npair) {
#pragma unroll
            for (int h2 = 0; h2 < 2; h2++)
#pragma unroll
              for (int r = 0; r < 4; r++) {
                float e = __expf(p[2 * ip + h2][r] - m_i);
                p[2 * ip + h2][r] = e;
                sum += e;
              }
          }
        l_i += sum;

#pragma unroll
        for (int ip = 0; ip < 2; ip++)
          if (ip < npair) {
            bf16x8 pf;
#pragma unroll
            for (int h2 = 0; h2 < 2; h2++)
#pragma unroll
              for (int r = 0; r < 4; r++) pf[4 * h2 + r] = (bf16)p[2 * ip + h2][r];
#pragma unroll
            for (int dt = 0; dt < 4; dt++) {
              const bf16x8 vf = *(const bf16x8*)(
                  Vc + (dt * 16 + l15) * 128 + (((4 * ip + g) ^ (l15 >> 1)) << 4));
              ot[dt] = MFMA_BF16(vf, pf, ot[dt], 0, 0, 0);
            }
          }
      }
      cur ^= 1;
    }

    l_i += __shfl_xor(l_i, 16, 64);
    l_i += __shfl_xor(l_i, 32, 64);
    const float inv = 1.0f / l_i;
    bf16* obase = O + (tokbase + qw0 + l15) * 1024 + hh * 64;
#pragma unroll
    for (int dt = 0; dt < 4; dt++) {
      bf16x4 ov;
#pragma unroll
      for (int r = 0; r < 4; r++) ov[r] = (bf16)(ot[dt][r] * inv);
      *(bf16x4*)(obase + dt * 16 + 4 * g) = ov;
    }
  }
}

// ---------------------------------------------------------------- launch
extern "C" void kernel_launch(void* const* d_in, const int* in_sizes, int n_in,
                              void* d_out, int out_size, void* d_ws, size_t ws_size,
                              hipStream_t stream) {
  const float* x = (const float*)d_in[0];
  const float* w_qkv = (const float*)d_in[1];
  const float* w_out = (const float*)d_in[2];
  const float* w_ff1 = (const float*)d_in[3];
  const float* w_ff2 = (const float*)d_in[4];
  float* out = (float*)d_out;

  char* ws = (char*)d_ws;
  size_t off = 0;
  auto alloc = [&](size_t bytes) {
    void* p = ws + off;
    off += (bytes + 255) & ~(size_t)255;
    return p;
  };
  const size_t M = 8192;
  bf16* X16   = (bf16*)alloc(M * 1024 * 2);
  bf16* WqkvT = (bf16*)alloc(3072ull * 1024 * 2);
  bf16* WoutT = (bf16*)alloc(1024ull * 1024 * 2);
  bf16* Wff1T = (bf16*)alloc(4096ull * 1024 * 2);
  bf16* Wff2T = (bf16*)alloc(1024ull * 4096 * 2);
  bf16* QKV   = (bf16*)alloc(M * 3072 * 2);
  bf16* Obuf  = (bf16*)alloc(M * 1024 * 2);
  bf16* x1b   = (bf16*)alloc(M * 1024 * 2);
  bf16* Hbuf  = (bf16*)alloc(M * 4096 * 2);

  cvt_f32_bf16<<<8192, 256, 0, stream>>>(x, X16, 8192 * 1024);
  transpose_w<<<dim3(3072 / 32, 1024 / 32), 256, 0, stream>>>(w_qkv, WqkvT, 1024, 3072);
  transpose_w<<<dim3(1024 / 32, 1024 / 32), 256, 0, stream>>>(w_out, WoutT, 1024, 1024);
  transpose_w<<<dim3(4096 / 32, 1024 / 32), 256, 0, stream>>>(w_ff1, Wff1T, 1024, 4096);
  transpose_w<<<dim3(1024 / 32, 4096 / 32), 256, 0, stream>>>(w_ff2, Wff2T, 4096, 1024);

  gemm_bt<0, 64><<<64 * 24, 256, 0, stream>>>(X16, WqkvT, QKV, nullptr, nullptr, 1024, 3072);
  attn_fwd<<<dim3(64, 8), 512, 0, stream>>>(QKV, Obuf);
  gemm_bt<1, 128><<<64 * 8, 256, 0, stream>>>(Obuf, WoutT, x1b, nullptr, X16, 1024, 1024);
  gemm_bt<2, 64><<<64 * 32, 256, 0, stream>>>(x1b, Wff1T, Hbuf, nullptr, nullptr, 1024, 4096);
  gemm_bt<3, 128><<<64 * 8, 256, 0, stream>>>(Hbuf, Wff2T, nullptr, out, x1b, 4096, 1024);
}